// Round 1
// baseline (697.038 us; speedup 1.0000x reference)
//
#include <hip/hip_runtime.h>
#include <cstddef>

// ---------------- constants ----------------
#define NXI   512
#define LL    128
#define NST   128
#define NU    64
#define BATCH 32768
#define TW    1152          // 2n + l
#define EPSC  0.001f
#define KC    768           // concat K: xi(512) | eps(128) | w(128)
#define NC    576           // concat N: xi'(512) | u(64)

typedef unsigned short u16;
typedef __attribute__((ext_vector_type(8))) short   short8;
typedef __attribute__((ext_vector_type(4))) short   short4v;
typedef __attribute__((ext_vector_type(4))) float   f32x4;

__device__ __forceinline__ u16 f2bf(float f) {
    unsigned u = __float_as_uint(f);
    u += 0x7FFFu + ((u >> 16) & 1u);   // RNE
    return (u16)(u >> 16);
}

// ---------------- transpose+convert X -> XT (bf16), XT[i][k] = X[k][i] ----------------
__global__ __launch_bounds__(256) void k_transpose(const float* __restrict__ X, u16* __restrict__ XT) {
    __shared__ float t[32][33];
    int tx = threadIdx.x & 31, ty = threadIdx.x >> 5;
    int bx = blockIdx.x, by = blockIdx.y;
    #pragma unroll
    for (int q = 0; q < 4; q++) {
        int r = ty + q * 8;
        t[r][tx] = X[(size_t)(by * 32 + r) * TW + bx * 32 + tx];
    }
    __syncthreads();
    #pragma unroll
    for (int q = 0; q < 4; q++) {
        int r = ty + q * 8;
        XT[(size_t)(bx * 32 + r) * TW + by * 32 + tx] = f2bf(t[tx][r]);
    }
}

// ---------------- build Ac = [bf16(xi) | 0 | bf16(w)] (BATCH x 768) ----------------
__global__ __launch_bounds__(256) void k_build_Ac(const float* __restrict__ xi, const float* __restrict__ w,
                                                  u16* __restrict__ Ac) {
    size_t idx = ((size_t)blockIdx.x * 256 + threadIdx.x) * 8;
    int b = (int)(idx / KC), c = (int)(idx % KC);
    float v[8];
    if (c < 512) {
        const f32x4* s = (const f32x4*)(xi + (size_t)b * NXI + c);
        f32x4 a = s[0], bb = s[1];
        v[0]=a[0]; v[1]=a[1]; v[2]=a[2]; v[3]=a[3]; v[4]=bb[0]; v[5]=bb[1]; v[6]=bb[2]; v[7]=bb[3];
    } else if (c < 640) {
        #pragma unroll
        for (int j = 0; j < 8; j++) v[j] = 0.f;
    } else {
        const f32x4* s = (const f32x4*)(w + (size_t)b * NST + (c - 640));
        f32x4 a = s[0], bb = s[1];
        v[0]=a[0]; v[1]=a[1]; v[2]=a[2]; v[3]=a[3]; v[4]=bb[0]; v[5]=bb[1]; v[6]=bb[2]; v[7]=bb[3];
    }
    short8 o;
    #pragma unroll
    for (int j = 0; j < 8; j++) o[j] = (short)f2bf(v[j]);
    *(short8*)(Ac + idx) = o;
}

// ---------------- generic bf16 MFMA GEMM: C = A @ W^T ----------------
// BM=128 BN=64 BK=32, 256 threads (4 waves), wave w owns rows [32w,32w+32), all 64 cols.
// Output split: col < nsplit -> C0[row*ldc0+col] ; else C1[row*ldc1+col-nsplit]
#define LDT 40  // LDS row stride in bf16 (80B) -> <=2-way bank aliasing on b128 frag reads
__global__ __launch_bounds__(256) void k_gemm(const u16* __restrict__ A, int lda,
                                              const u16* __restrict__ W, int ldw,
                                              float* __restrict__ C0, int ldc0, int nsplit,
                                              float* __restrict__ C1, int ldc1, int K) {
    __shared__ __align__(16) u16 As[128 * LDT];
    __shared__ __align__(16) u16 Bs[64 * LDT];
    int tid = threadIdx.x;
    int wave = tid >> 6, lane = tid & 63, quad = lane >> 4, l16 = lane & 15;
    int bm0 = blockIdx.y * 128, bn0 = blockIdx.x * 64;
    f32x4 acc[2][4];
    #pragma unroll
    for (int i = 0; i < 2; i++)
        #pragma unroll
        for (int j = 0; j < 4; j++) acc[i][j] = (f32x4){0.f, 0.f, 0.f, 0.f};

    int sr = tid >> 1, sh = tid & 1;
    for (int kt = 0; kt < K; kt += 32) {
        __syncthreads();
        {
            const f32x4* sa = (const f32x4*)(A + (size_t)(bm0 + sr) * lda + kt + sh * 16);
            f32x4 v0 = sa[0], v1 = sa[1];
            f32x4* da = (f32x4*)&As[sr * LDT + sh * 16];
            da[0] = v0; da[1] = v1;
            if (tid < 128) {
                int br = tid >> 1, bh = tid & 1;
                const f32x4* sb = (const f32x4*)(W + (size_t)(bn0 + br) * ldw + kt + bh * 16);
                f32x4 u0 = sb[0], u1 = sb[1];
                f32x4* db = (f32x4*)&Bs[br * LDT + bh * 16];
                db[0] = u0; db[1] = u1;
            }
        }
        __syncthreads();
        short8 af0 = *(const short8*)&As[(wave * 32 + l16) * LDT + quad * 8];
        short8 af1 = *(const short8*)&As[(wave * 32 + 16 + l16) * LDT + quad * 8];
        #pragma unroll
        for (int nt = 0; nt < 4; nt++) {
            short8 wf = *(const short8*)&Bs[(nt * 16 + l16) * LDT + quad * 8];
            acc[0][nt] = __builtin_amdgcn_mfma_f32_16x16x32_bf16(af0, wf, acc[0][nt], 0, 0, 0);
            acc[1][nt] = __builtin_amdgcn_mfma_f32_16x16x32_bf16(af1, wf, acc[1][nt], 0, 0, 0);
        }
    }
    // epilogue: D[row=quad*4+r][col=l16] per 16x16 tile (m89-verified layout)
    #pragma unroll
    for (int mt = 0; mt < 2; mt++)
        #pragma unroll
        for (int nt = 0; nt < 4; nt++)
            #pragma unroll
            for (int r = 0; r < 4; r++) {
                int row = bm0 + wave * 32 + mt * 16 + quad * 4 + r;
                int col = bn0 + nt * 16 + l16;
                float v = acc[mt][nt][r];
                if (col < nsplit) C0[(size_t)row * ldc0 + col] = v;
                else              C1[(size_t)row * ldc1 + (col - nsplit)] = v;
            }
}

// ---------------- derive params from H, build GJ-augmented [E | Fm B1 B2], D11, rlam, W1 ----------------
__global__ __launch_bounds__(256) void k_derive(const float* __restrict__ Hm, const float* __restrict__ Y,
                                                const float* __restrict__ B2, const float* __restrict__ D12,
                                                float* __restrict__ Agj, float* __restrict__ D11,
                                                float* __restrict__ rlam, u16* __restrict__ W1) {
    int idx = blockIdx.x * 256 + threadIdx.x;
    const int n0 = 512 * 1280, n1 = 128 * 128, n2 = 128, n3 = 128 * KC;
    if (idx < n0) {
        int i = idx / 1280, j = idx % 1280;
        float val;
        if (j < 512) {
            val = 0.5f * (Hm[(size_t)i * TW + j] + Hm[(size_t)(640 + i) * TW + 640 + j]
                          + Y[(size_t)i * 512 + j] - Y[(size_t)j * 512 + i]);
            if (i == j) val += EPSC;
        } else if (j < 1024) {
            val = Hm[(size_t)(640 + i) * TW + (j - 512)];           // Fm = H31
        } else if (j < 1152) {
            val = Hm[(size_t)(640 + i) * TW + 512 + (j - 1024)];    // B1 = H32
        } else {
            val = B2[(size_t)i * NST + (j - 1152)];
        }
        Agj[idx] = val;
        return;
    }
    idx -= n0;
    if (idx < n1) {
        int i = idx >> 7, j = idx & 127;
        D11[idx] = (j < i) ? -Hm[(size_t)(512 + i) * TW + 512 + j] : 0.f;  // -tril(H22,-1)
        return;
    }
    idx -= n1;
    if (idx < n2) {
        rlam[idx] = 2.0f / (Hm[(size_t)(512 + idx) * TW + 512 + idx] + EPSC);  // 1/(0.5*diag(H22))
        return;
    }
    idx -= n2;
    if (idx < n3) {
        int i = idx / KC, c = idx % KC;
        float v;
        if (c < 512)      v = -Hm[(size_t)(512 + i) * TW + c];      // C1 = -H21
        else if (c < 640) v = 0.f;                                  // eps slot unused for pre
        else              v = D12[(size_t)i * NST + (c - 640)];
        W1[(size_t)i * KC + c] = f2bf(v);
    }
}

// ---------------- 64x64 in-block Gauss-Jordan inverse (no pivoting) ----------------
// thread -> (row r = tid>>2, col chunk c = tid&3, 16 cols each), matrix in LDS (stride 68)
__device__ __forceinline__ void invert64(float* Cl, float* Sa, float* Sb, float* mcol,
                                         float* rp, float* __restrict__ invOut, int tid) {
    int r = tid >> 2, c = tid & 3;
    float a[16], b[16];
    #pragma unroll
    for (int q = 0; q < 4; q++) {
        f32x4 v = *(f32x4*)&Cl[r * 68 + c * 16 + q * 4];
        a[q*4+0]=v[0]; a[q*4+1]=v[1]; a[q*4+2]=v[2]; a[q*4+3]=v[3];
    }
    #pragma unroll
    for (int j = 0; j < 16; j++) b[j] = (c * 16 + j == r) ? 1.f : 0.f;

    #pragma unroll
    for (int k = 0; k < 64; k++) {
        const int kc = k >> 4, kl = k & 15;
        if (r == k) {
            #pragma unroll
            for (int q = 0; q < 4; q++) {
                *(f32x4*)&Sa[c * 16 + q * 4] = (f32x4){a[q*4], a[q*4+1], a[q*4+2], a[q*4+3]};
                *(f32x4*)&Sb[c * 16 + q * 4] = (f32x4){b[q*4], b[q*4+1], b[q*4+2], b[q*4+3]};
            }
        }
        if (c == kc) {
            mcol[r] = a[kl];
            if (r == k) rp[0] = 1.0f / a[kl];
        }
        __syncthreads();
        float m = (mcol[r] - ((r == k) ? 1.0f : 0.0f)) * rp[0];
        #pragma unroll
        for (int q = 0; q < 4; q++) {
            f32x4 sa = *(f32x4*)&Sa[c * 16 + q * 4];
            f32x4 sb = *(f32x4*)&Sb[c * 16 + q * 4];
            a[q*4+0] = fmaf(-m, sa[0], a[q*4+0]); a[q*4+1] = fmaf(-m, sa[1], a[q*4+1]);
            a[q*4+2] = fmaf(-m, sa[2], a[q*4+2]); a[q*4+3] = fmaf(-m, sa[3], a[q*4+3]);
            b[q*4+0] = fmaf(-m, sb[0], b[q*4+0]); b[q*4+1] = fmaf(-m, sb[1], b[q*4+1]);
            b[q*4+2] = fmaf(-m, sb[2], b[q*4+2]); b[q*4+3] = fmaf(-m, sb[3], b[q*4+3]);
        }
        __syncthreads();
    }
    #pragma unroll
    for (int q = 0; q < 4; q++)
        *(f32x4*)&invOut[r * 64 + c * 16 + q * 4] = (f32x4){b[q*4], b[q*4+1], b[q*4+2], b[q*4+3]};
}

__global__ __launch_bounds__(256) void k_diaginv0(const float* __restrict__ Agj, float* __restrict__ invD) {
    __shared__ __align__(16) float Cl[64 * 68];
    __shared__ float Sa[64], Sb[64], mcol[64], rp[1];
    int tid = threadIdx.x, r = tid >> 2, c4 = tid & 3;
    #pragma unroll
    for (int q = 0; q < 4; q++)
        *(f32x4*)&Cl[r * 68 + c4 * 16 + q * 4] = *(const f32x4*)(Agj + (size_t)r * 1280 + c4 * 16 + q * 4);
    __syncthreads();
    invert64(Cl, Sa, Sb, mcol, rp, invD, tid);
}

// ---------------- GJ eliminate step k (deferred pivot-row scaling; multipliers frozen in col k) ----------------
// grid: x = 19-k (cb = k+1+bx), y = 7 (rb = all row blocks != k). Block updating next diag tile also inverts it.
__global__ __launch_bounds__(256) void k_elim(float* __restrict__ Agj, float* __restrict__ invD, int k) {
    __shared__ __align__(16) float invDs[64 * 68];
    __shared__ __align__(16) float Ps[64 * 68];
    __shared__ __align__(16) float Ss[64 * 68];
    __shared__ __align__(16) float Ms[64 * 68];
    __shared__ float Sa[64], Sb[64], mcol[64], rp[1];
    int tid = threadIdx.x;
    int by = blockIdx.y, bx = blockIdx.x;
    int rb = by + (by >= k ? 1 : 0);
    int cb = k + 1 + bx;
    int lr = tid >> 2, lc = tid & 3;
    #pragma unroll
    for (int q = 0; q < 4; q++) {
        *(f32x4*)&invDs[lr * 68 + lc * 16 + q * 4] = *(const f32x4*)(invD + (size_t)k * 4096 + lr * 64 + lc * 16 + q * 4);
        *(f32x4*)&Ps[lr * 68 + lc * 16 + q * 4]    = *(const f32x4*)(Agj + (size_t)(k * 64 + lr) * 1280 + cb * 64 + lc * 16 + q * 4);
        *(f32x4*)&Ms[lr * 68 + lc * 16 + q * 4]    = *(const f32x4*)(Agj + (size_t)(rb * 64 + lr) * 1280 + k * 64 + lc * 16 + q * 4);
    }
    __syncthreads();
    int ty = tid >> 4, tx = tid & 15;
    // S = invD_k @ P  (scaled pivot row tile, computed redundantly per block)
    f32x4 s[4];
    #pragma unroll
    for (int ri = 0; ri < 4; ri++) s[ri] = (f32x4){0.f, 0.f, 0.f, 0.f};
    for (int kk = 0; kk < 64; kk++) {
        f32x4 pv = *(f32x4*)&Ps[kk * 68 + tx * 4];
        #pragma unroll
        for (int ri = 0; ri < 4; ri++) s[ri] += pv * invDs[(ty * 4 + ri) * 68 + kk];
    }
    #pragma unroll
    for (int ri = 0; ri < 4; ri++) *(f32x4*)&Ss[(ty * 4 + ri) * 68 + tx * 4] = s[ri];
    __syncthreads();
    // C -= M @ S
    f32x4 accv[4];
    #pragma unroll
    for (int ri = 0; ri < 4; ri++)
        accv[ri] = *(const f32x4*)(Agj + (size_t)(rb * 64 + ty * 4 + ri) * 1280 + cb * 64 + tx * 4);
    for (int kk = 0; kk < 64; kk++) {
        f32x4 sv = *(f32x4*)&Ss[kk * 68 + tx * 4];
        #pragma unroll
        for (int ri = 0; ri < 4; ri++) accv[ri] -= sv * Ms[(ty * 4 + ri) * 68 + kk];
    }
    #pragma unroll
    for (int ri = 0; ri < 4; ri++)
        *(f32x4*)(Agj + (size_t)(rb * 64 + ty * 4 + ri) * 1280 + cb * 64 + tx * 4) = accv[ri];
    // fused: invert the next pivot diagonal tile (rb==cb==k+1) while rest of GPU runs other tiles
    if (k < 7 && bx == 0 && by == k) {
        __syncthreads();
        #pragma unroll
        for (int ri = 0; ri < 4; ri++) *(f32x4*)&Ps[(ty * 4 + ri) * 68 + tx * 4] = accv[ri];
        __syncthreads();
        invert64(Ps, Sa, Sb, mcol, rp, invD + (size_t)(k + 1) * 4096, tid);
    }
}

// ---------------- finalize: Wc rows 0..511 = invD_k @ Agj[pivot rows, 512:1280] (bf16); rows 512..575 from C2|D21|D22 ----------------
__global__ __launch_bounds__(256) void k_finalize(const float* __restrict__ Agj, const float* __restrict__ invD,
                                                  const float* __restrict__ C2, const float* __restrict__ D21,
                                                  const float* __restrict__ D22, u16* __restrict__ Wc) {
    __shared__ __align__(16) float invDs[64 * 68];
    __shared__ __align__(16) float Ps[64 * 68];
    int tid = threadIdx.x, bx = blockIdx.x, by = blockIdx.y;
    int ty = tid >> 4, tx = tid & 15;
    if (by == 8) {
        #pragma unroll
        for (int ri = 0; ri < 4; ri++) {
            int q = ty * 4 + ri;
            int cbase = bx * 64 + tx * 4;
            f32x4 v;
            if (cbase < 512)      v = *(const f32x4*)(C2 + (size_t)q * 512 + cbase);
            else if (cbase < 640) v = *(const f32x4*)(D21 + (size_t)q * NST + (cbase - 512));
            else                  v = *(const f32x4*)(D22 + (size_t)q * NST + (cbase - 640));
            short4v o; o[0]=(short)f2bf(v[0]); o[1]=(short)f2bf(v[1]); o[2]=(short)f2bf(v[2]); o[3]=(short)f2bf(v[3]);
            *(short4v*)(Wc + (size_t)(512 + q) * KC + cbase) = o;
        }
        return;
    }
    int lr = tid >> 2, lc = tid & 3;
    #pragma unroll
    for (int q = 0; q < 4; q++) {
        *(f32x4*)&invDs[lr * 68 + lc * 16 + q * 4] = *(const f32x4*)(invD + (size_t)by * 4096 + lr * 64 + lc * 16 + q * 4);
        *(f32x4*)&Ps[lr * 68 + lc * 16 + q * 4]    = *(const f32x4*)(Agj + (size_t)(by * 64 + lr) * 1280 + 512 + bx * 64 + lc * 16 + q * 4);
    }
    __syncthreads();
    f32x4 s[4];
    #pragma unroll
    for (int ri = 0; ri < 4; ri++) s[ri] = (f32x4){0.f, 0.f, 0.f, 0.f};
    for (int kk = 0; kk < 64; kk++) {
        f32x4 pv = *(f32x4*)&Ps[kk * 68 + tx * 4];
        #pragma unroll
        for (int ri = 0; ri < 4; ri++) s[ri] += pv * invDs[(ty * 4 + ri) * 68 + kk];
    }
    #pragma unroll
    for (int ri = 0; ri < 4; ri++) {
        short4v o; o[0]=(short)f2bf(s[ri][0]); o[1]=(short)f2bf(s[ri][1]); o[2]=(short)f2bf(s[ri][2]); o[3]=(short)f2bf(s[ri][3]);
        *(short4v*)(Wc + (size_t)(by * 64 + ty * 4 + ri) * KC + bx * 64 + tx * 4) = o;
    }
}

// ---------------- sequential tanh scan (forward substitution), 16 lanes per batch row ----------------
// eps[i] = tanh( (pre[b,i] + sum_{j<i} eps[j]*D11[i][j]) / Lam[i] ); writes bf16 eps into Ac cols 512:640
__global__ __launch_bounds__(256) void k_scan(const float* __restrict__ pre, const float* __restrict__ D11,
                                              const float* __restrict__ rlam, u16* __restrict__ Ac) {
    __shared__ float D11s[128 * 128];
    __shared__ float rl[128];
    int tid = threadIdx.x;
    #pragma unroll
    for (int q = 0; q < 16; q++)
        ((f32x4*)D11s)[q * 256 + tid] = ((const f32x4*)D11)[q * 256 + tid];
    if (tid < 32) ((f32x4*)rl)[tid] = ((const f32x4*)rlam)[tid];
    __syncthreads();
    int wave = tid >> 6, lane = tid & 63, g = lane >> 4, lg = lane & 15;
    for (int it = 0; it < 4; it++) {
        int row = blockIdx.x * 64 + it * 16 + wave * 4 + g;
        const f32x4* pp = (const f32x4*)(pre + (size_t)row * 128 + lg * 8);
        f32x4 p0 = pp[0], p1 = pp[1];
        float p[8] = {p0[0], p0[1], p0[2], p0[3], p1[0], p1[1], p1[2], p1[3]};
        float e8[8] = {0.f, 0.f, 0.f, 0.f, 0.f, 0.f, 0.f, 0.f};
        for (int i8 = 0; i8 < 16; i8++) {
            #pragma unroll
            for (int ii = 0; ii < 8; ii++) {
                int i = i8 * 8 + ii;
                const f32x4* dd = (const f32x4*)&D11s[i * 128 + lg * 8];
                f32x4 d0 = dd[0], d1 = dd[1];
                float t = e8[0]*d0[0] + e8[1]*d0[1] + e8[2]*d0[2] + e8[3]*d0[3]
                        + e8[4]*d1[0] + e8[5]*d1[1] + e8[6]*d1[2] + e8[7]*d1[3];
                if (lg == i8) t += p[ii];
                t += __shfl_xor(t, 1); t += __shfl_xor(t, 2);
                t += __shfl_xor(t, 4); t += __shfl_xor(t, 8);
                float e = tanhf(t * rl[i]);
                if (lg == i8) e8[ii] = e;
            }
        }
        short8 o;
        #pragma unroll
        for (int j = 0; j < 8; j++) o[j] = (short)f2bf(e8[j]);
        *(short8*)(Ac + (size_t)row * KC + 512 + lg * 8) = o;
    }
}

// ---------------- host ----------------
extern "C" void kernel_launch(void* const* d_in, const int* in_sizes, int n_in,
                              void* d_out, int out_size, void* d_ws, size_t ws_size,
                              hipStream_t stream) {
    const float* w_in  = (const float*)d_in[1];
    const float* xi_in = (const float*)d_in[2];
    const float* X   = (const float*)d_in[3];
    const float* Y   = (const float*)d_in[4];
    const float* B2  = (const float*)d_in[5];
    const float* C2  = (const float*)d_in[6];
    const float* D21 = (const float*)d_in[7];
    const float* D22 = (const float*)d_in[8];
    const float* D12 = (const float*)d_in[9];
    float* out_u  = (float*)d_out;                       // (BATCH,1,64)
    float* out_xi = (float*)d_out + (size_t)BATCH * NU;  // (BATCH,1,512)

    char* base = (char*)d_ws;
    size_t off = 0;
    auto carve = [&](size_t bytes) -> void* {
        void* p = base + off;
        off += (bytes + 255) & ~(size_t)255;
        return p;
    };
    u16*   XT   = (u16*)  carve((size_t)TW * TW * 2);
    u16*   Ac   = (u16*)  carve((size_t)BATCH * KC * 2);
    float* Hm   = (float*)carve((size_t)TW * TW * 4);
    float* Agj  = (float*)carve((size_t)512 * 1280 * 4);
    float* invD = (float*)carve((size_t)8 * 64 * 64 * 4);
    u16*   Wc   = (u16*)  carve((size_t)NC * KC * 2);
    u16*   W1   = (u16*)  carve((size_t)LL * KC * 2);
    float* pre  = (float*)carve((size_t)BATCH * LL * 4);
    float* D11  = (float*)carve((size_t)LL * LL * 4);
    float* rlam = (float*)carve((size_t)LL * 4);
    (void)ws_size; (void)in_sizes; (void)n_in; (void)out_size;

    // setup chain
    k_transpose<<<dim3(36, 36), 256, 0, stream>>>(X, XT);
    k_build_Ac<<<(BATCH * KC / 8 + 255) / 256, 256, 0, stream>>>(xi_in, w_in, Ac);
    // H = X^T X  (bf16 MFMA; +eps*I applied in k_derive)
    k_gemm<<<dim3(TW / 64, TW / 128), 256, 0, stream>>>(XT, TW, XT, TW, Hm, TW, 1 << 30, nullptr, 0, TW);
    k_derive<<<(512 * 1280 + 128 * 128 + 128 + 128 * KC + 255) / 256, 256, 0, stream>>>(
        Hm, Y, B2, D12, Agj, D11, rlam, W1);
    // blocked Gauss-Jordan on [E | Fm B1 B2] with fused next-diag inversion
    k_diaginv0<<<1, 256, 0, stream>>>(Agj, invD);
    for (int k = 0; k < 8; k++)
        k_elim<<<dim3(19 - k, 7), 256, 0, stream>>>(Agj, invD, k);
    k_finalize<<<dim3(12, 9), 256, 0, stream>>>(Agj, invD, C2, D21, D22, Wc);
    // batch side
    k_gemm<<<dim3(LL / 64, BATCH / 128), 256, 0, stream>>>(Ac, KC, W1, KC, pre, LL, 1 << 30, nullptr, 0, KC);
    k_scan<<<BATCH / 64, 256, 0, stream>>>(pre, D11, rlam, Ac);
    k_gemm<<<dim3(NC / 64, BATCH / 128), 256, 0, stream>>>(Ac, KC, Wc, KC, out_xi, NXI, 512, out_u, NU, KC);
}

// Round 2
// 580.509 us; speedup vs baseline: 1.2007x; 1.2007x over previous
//
#include <hip/hip_runtime.h>
#include <cstddef>

// ---------------- constants ----------------
#define NXI   512
#define LL    128
#define NST   128
#define NU    64
#define BATCH 32768
#define TW    1152          // 2n + l
#define EPSC  0.001f
#define KC    768           // concat K: xi(512) | eps(128) | w(128)
#define NC    576           // concat N: xi'(512) | u(64)

typedef unsigned short u16;
typedef __attribute__((ext_vector_type(8))) short   short8;
typedef __attribute__((ext_vector_type(4))) short   short4v;
typedef __attribute__((ext_vector_type(4))) float   f32x4;

__device__ __forceinline__ u16 f2bf(float f) {
    unsigned u = __float_as_uint(f);
    u += 0x7FFFu + ((u >> 16) & 1u);   // RNE
    return (u16)(u >> 16);
}

// ---------------- transpose+convert X -> XT (bf16), XT[i][k] = X[k][i] ----------------
__global__ __launch_bounds__(256) void k_transpose(const float* __restrict__ X, u16* __restrict__ XT) {
    __shared__ float t[32][33];
    int tx = threadIdx.x & 31, ty = threadIdx.x >> 5;
    int bx = blockIdx.x, by = blockIdx.y;
    #pragma unroll
    for (int q = 0; q < 4; q++) {
        int r = ty + q * 8;
        t[r][tx] = X[(size_t)(by * 32 + r) * TW + bx * 32 + tx];
    }
    __syncthreads();
    #pragma unroll
    for (int q = 0; q < 4; q++) {
        int r = ty + q * 8;
        XT[(size_t)(bx * 32 + r) * TW + by * 32 + tx] = f2bf(t[tx][r]);
    }
}

// ---------------- build Ac = [bf16(xi) | 0 | bf16(w)] (BATCH x 768) ----------------
__global__ __launch_bounds__(256) void k_build_Ac(const float* __restrict__ xi, const float* __restrict__ w,
                                                  u16* __restrict__ Ac) {
    size_t idx = ((size_t)blockIdx.x * 256 + threadIdx.x) * 8;
    int b = (int)(idx / KC), c = (int)(idx % KC);
    float v[8];
    if (c < 512) {
        const f32x4* s = (const f32x4*)(xi + (size_t)b * NXI + c);
        f32x4 a = s[0], bb = s[1];
        v[0]=a[0]; v[1]=a[1]; v[2]=a[2]; v[3]=a[3]; v[4]=bb[0]; v[5]=bb[1]; v[6]=bb[2]; v[7]=bb[3];
    } else if (c < 640) {
        #pragma unroll
        for (int j = 0; j < 8; j++) v[j] = 0.f;
    } else {
        const f32x4* s = (const f32x4*)(w + (size_t)b * NST + (c - 640));
        f32x4 a = s[0], bb = s[1];
        v[0]=a[0]; v[1]=a[1]; v[2]=a[2]; v[3]=a[3]; v[4]=bb[0]; v[5]=bb[1]; v[6]=bb[2]; v[7]=bb[3];
    }
    short8 o;
    #pragma unroll
    for (int j = 0; j < 8; j++) o[j] = (short)f2bf(v[j]);
    *(short8*)(Ac + idx) = o;
}

// ---------------- generic bf16 MFMA GEMM: C = A @ W^T ----------------
// BM=128 BN=64 BK=32, 256 threads (4 waves), wave w owns rows [32w,32w+32), all 64 cols.
// Output split: col < nsplit -> C0[row*ldc0+col] ; else C1[row*ldc1+col-nsplit]
#define LDT 40  // LDS row stride in bf16 (80B) -> <=2-way bank aliasing on b128 frag reads
__global__ __launch_bounds__(256) void k_gemm(const u16* __restrict__ A, int lda,
                                              const u16* __restrict__ W, int ldw,
                                              float* __restrict__ C0, int ldc0, int nsplit,
                                              float* __restrict__ C1, int ldc1, int K) {
    __shared__ __align__(16) u16 As[128 * LDT];
    __shared__ __align__(16) u16 Bs[64 * LDT];
    int tid = threadIdx.x;
    int wave = tid >> 6, lane = tid & 63, quad = lane >> 4, l16 = lane & 15;
    int bm0 = blockIdx.y * 128, bn0 = blockIdx.x * 64;
    f32x4 acc[2][4];
    #pragma unroll
    for (int i = 0; i < 2; i++)
        #pragma unroll
        for (int j = 0; j < 4; j++) acc[i][j] = (f32x4){0.f, 0.f, 0.f, 0.f};

    int sr = tid >> 1, sh = tid & 1;
    for (int kt = 0; kt < K; kt += 32) {
        __syncthreads();
        {
            const f32x4* sa = (const f32x4*)(A + (size_t)(bm0 + sr) * lda + kt + sh * 16);
            f32x4 v0 = sa[0], v1 = sa[1];
            f32x4* da = (f32x4*)&As[sr * LDT + sh * 16];
            da[0] = v0; da[1] = v1;
            if (tid < 128) {
                int br = tid >> 1, bh = tid & 1;
                const f32x4* sb = (const f32x4*)(W + (size_t)(bn0 + br) * ldw + kt + bh * 16);
                f32x4 u0 = sb[0], u1 = sb[1];
                f32x4* db = (f32x4*)&Bs[br * LDT + bh * 16];
                db[0] = u0; db[1] = u1;
            }
        }
        __syncthreads();
        short8 af0 = *(const short8*)&As[(wave * 32 + l16) * LDT + quad * 8];
        short8 af1 = *(const short8*)&As[(wave * 32 + 16 + l16) * LDT + quad * 8];
        #pragma unroll
        for (int nt = 0; nt < 4; nt++) {
            short8 wf = *(const short8*)&Bs[(nt * 16 + l16) * LDT + quad * 8];
            acc[0][nt] = __builtin_amdgcn_mfma_f32_16x16x32_bf16(af0, wf, acc[0][nt], 0, 0, 0);
            acc[1][nt] = __builtin_amdgcn_mfma_f32_16x16x32_bf16(af1, wf, acc[1][nt], 0, 0, 0);
        }
    }
    // epilogue: D[row=quad*4+r][col=l16] per 16x16 tile (m89-verified layout)
    #pragma unroll
    for (int mt = 0; mt < 2; mt++)
        #pragma unroll
        for (int nt = 0; nt < 4; nt++)
            #pragma unroll
            for (int r = 0; r < 4; r++) {
                int row = bm0 + wave * 32 + mt * 16 + quad * 4 + r;
                int col = bn0 + nt * 16 + l16;
                float v = acc[mt][nt][r];
                if (col < nsplit) C0[(size_t)row * ldc0 + col] = v;
                else              C1[(size_t)row * ldc1 + (col - nsplit)] = v;
            }
}

// ---------------- derive params from H, build GJ-augmented [E | Fm B1 B2], D11, rlam, W1 ----------------
__global__ __launch_bounds__(256) void k_derive(const float* __restrict__ Hm, const float* __restrict__ Y,
                                                const float* __restrict__ B2, const float* __restrict__ D12,
                                                float* __restrict__ Agj, float* __restrict__ D11,
                                                float* __restrict__ rlam, u16* __restrict__ W1) {
    int idx = blockIdx.x * 256 + threadIdx.x;
    const int n0 = 512 * 1280, n1 = 128 * 128, n2 = 128, n3 = 128 * KC;
    if (idx < n0) {
        int i = idx / 1280, j = idx % 1280;
        float val;
        if (j < 512) {
            val = 0.5f * (Hm[(size_t)i * TW + j] + Hm[(size_t)(640 + i) * TW + 640 + j]
                          + Y[(size_t)i * 512 + j] - Y[(size_t)j * 512 + i]);
            if (i == j) val += EPSC;
        } else if (j < 1024) {
            val = Hm[(size_t)(640 + i) * TW + (j - 512)];           // Fm = H31
        } else if (j < 1152) {
            val = Hm[(size_t)(640 + i) * TW + 512 + (j - 1024)];    // B1 = H32
        } else {
            val = B2[(size_t)i * NST + (j - 1152)];
        }
        Agj[idx] = val;
        return;
    }
    idx -= n0;
    if (idx < n1) {
        int i = idx >> 7, j = idx & 127;
        D11[idx] = (j < i) ? -Hm[(size_t)(512 + i) * TW + 512 + j] : 0.f;  // -tril(H22,-1)
        return;
    }
    idx -= n1;
    if (idx < n2) {
        rlam[idx] = 2.0f / (Hm[(size_t)(512 + idx) * TW + 512 + idx] + EPSC);  // 1/(0.5*diag(H22))
        return;
    }
    idx -= n2;
    if (idx < n3) {
        int i = idx / KC, c = idx % KC;
        float v;
        if (c < 512)      v = -Hm[(size_t)(512 + i) * TW + c];      // C1 = -H21
        else if (c < 640) v = 0.f;                                  // eps slot unused for pre
        else              v = D12[(size_t)i * NST + (c - 640)];
        W1[(size_t)i * KC + c] = f2bf(v);
    }
}

// ---------------- 64x64 in-block Gauss-Jordan inverse (no pivoting) ----------------
// thread -> (row r = tid>>2, col chunk c = tid&3, 16 cols each), matrix in LDS (stride 68)
__device__ __forceinline__ void invert64(float* Cl, float* Sa, float* Sb, float* mcol,
                                         float* rp, float* __restrict__ invOut, int tid) {
    int r = tid >> 2, c = tid & 3;
    float a[16], b[16];
    #pragma unroll
    for (int q = 0; q < 4; q++) {
        f32x4 v = *(f32x4*)&Cl[r * 68 + c * 16 + q * 4];
        a[q*4+0]=v[0]; a[q*4+1]=v[1]; a[q*4+2]=v[2]; a[q*4+3]=v[3];
    }
    #pragma unroll
    for (int j = 0; j < 16; j++) b[j] = (c * 16 + j == r) ? 1.f : 0.f;

    #pragma unroll
    for (int k = 0; k < 64; k++) {
        const int kc = k >> 4, kl = k & 15;
        if (r == k) {
            #pragma unroll
            for (int q = 0; q < 4; q++) {
                *(f32x4*)&Sa[c * 16 + q * 4] = (f32x4){a[q*4], a[q*4+1], a[q*4+2], a[q*4+3]};
                *(f32x4*)&Sb[c * 16 + q * 4] = (f32x4){b[q*4], b[q*4+1], b[q*4+2], b[q*4+3]};
            }
        }
        if (c == kc) {
            mcol[r] = a[kl];
            if (r == k) rp[0] = 1.0f / a[kl];
        }
        __syncthreads();
        float m = (mcol[r] - ((r == k) ? 1.0f : 0.0f)) * rp[0];
        #pragma unroll
        for (int q = 0; q < 4; q++) {
            f32x4 sa = *(f32x4*)&Sa[c * 16 + q * 4];
            f32x4 sb = *(f32x4*)&Sb[c * 16 + q * 4];
            a[q*4+0] = fmaf(-m, sa[0], a[q*4+0]); a[q*4+1] = fmaf(-m, sa[1], a[q*4+1]);
            a[q*4+2] = fmaf(-m, sa[2], a[q*4+2]); a[q*4+3] = fmaf(-m, sa[3], a[q*4+3]);
            b[q*4+0] = fmaf(-m, sb[0], b[q*4+0]); b[q*4+1] = fmaf(-m, sb[1], b[q*4+1]);
            b[q*4+2] = fmaf(-m, sb[2], b[q*4+2]); b[q*4+3] = fmaf(-m, sb[3], b[q*4+3]);
        }
        __syncthreads();
    }
    #pragma unroll
    for (int q = 0; q < 4; q++)
        *(f32x4*)&invOut[r * 64 + c * 16 + q * 4] = (f32x4){b[q*4], b[q*4+1], b[q*4+2], b[q*4+3]};
}

__global__ __launch_bounds__(256) void k_diaginv0(const float* __restrict__ Agj, float* __restrict__ invD) {
    __shared__ __align__(16) float Cl[64 * 68];
    __shared__ float Sa[64], Sb[64], mcol[64], rp[1];
    int tid = threadIdx.x, r = tid >> 2, c4 = tid & 3;
    #pragma unroll
    for (int q = 0; q < 4; q++)
        *(f32x4*)&Cl[r * 68 + c4 * 16 + q * 4] = *(const f32x4*)(Agj + (size_t)r * 1280 + c4 * 16 + q * 4);
    __syncthreads();
    invert64(Cl, Sa, Sb, mcol, rp, invD, tid);
}

// ---------------- GJ eliminate step k (deferred pivot-row scaling; multipliers frozen in col k) ----------------
// grid: x = 19-k (cb = k+1+bx), y = 7 (rb = all row blocks != k). Block updating next diag tile also inverts it.
__global__ __launch_bounds__(256) void k_elim(float* __restrict__ Agj, float* __restrict__ invD, int k) {
    __shared__ __align__(16) float invDs[64 * 68];
    __shared__ __align__(16) float Ps[64 * 68];
    __shared__ __align__(16) float Ss[64 * 68];
    __shared__ __align__(16) float Ms[64 * 68];
    __shared__ float Sa[64], Sb[64], mcol[64], rp[1];
    int tid = threadIdx.x;
    int by = blockIdx.y, bx = blockIdx.x;
    int rb = by + (by >= k ? 1 : 0);
    int cb = k + 1 + bx;
    int lr = tid >> 2, lc = tid & 3;
    #pragma unroll
    for (int q = 0; q < 4; q++) {
        *(f32x4*)&invDs[lr * 68 + lc * 16 + q * 4] = *(const f32x4*)(invD + (size_t)k * 4096 + lr * 64 + lc * 16 + q * 4);
        *(f32x4*)&Ps[lr * 68 + lc * 16 + q * 4]    = *(const f32x4*)(Agj + (size_t)(k * 64 + lr) * 1280 + cb * 64 + lc * 16 + q * 4);
        *(f32x4*)&Ms[lr * 68 + lc * 16 + q * 4]    = *(const f32x4*)(Agj + (size_t)(rb * 64 + lr) * 1280 + k * 64 + lc * 16 + q * 4);
    }
    __syncthreads();
    int ty = tid >> 4, tx = tid & 15;
    // S = invD_k @ P  (scaled pivot row tile, computed redundantly per block)
    f32x4 s[4];
    #pragma unroll
    for (int ri = 0; ri < 4; ri++) s[ri] = (f32x4){0.f, 0.f, 0.f, 0.f};
    for (int kk = 0; kk < 64; kk++) {
        f32x4 pv = *(f32x4*)&Ps[kk * 68 + tx * 4];
        #pragma unroll
        for (int ri = 0; ri < 4; ri++) s[ri] += pv * invDs[(ty * 4 + ri) * 68 + kk];
    }
    #pragma unroll
    for (int ri = 0; ri < 4; ri++) *(f32x4*)&Ss[(ty * 4 + ri) * 68 + tx * 4] = s[ri];
    __syncthreads();
    // C -= M @ S
    f32x4 accv[4];
    #pragma unroll
    for (int ri = 0; ri < 4; ri++)
        accv[ri] = *(const f32x4*)(Agj + (size_t)(rb * 64 + ty * 4 + ri) * 1280 + cb * 64 + tx * 4);
    for (int kk = 0; kk < 64; kk++) {
        f32x4 sv = *(f32x4*)&Ss[kk * 68 + tx * 4];
        #pragma unroll
        for (int ri = 0; ri < 4; ri++) accv[ri] -= sv * Ms[(ty * 4 + ri) * 68 + kk];
    }
    #pragma unroll
    for (int ri = 0; ri < 4; ri++)
        *(f32x4*)(Agj + (size_t)(rb * 64 + ty * 4 + ri) * 1280 + cb * 64 + tx * 4) = accv[ri];
    // fused: invert the next pivot diagonal tile (rb==cb==k+1) while rest of GPU runs other tiles
    if (k < 7 && bx == 0 && by == k) {
        __syncthreads();
        #pragma unroll
        for (int ri = 0; ri < 4; ri++) *(f32x4*)&Ps[(ty * 4 + ri) * 68 + tx * 4] = accv[ri];
        __syncthreads();
        invert64(Ps, Sa, Sb, mcol, rp, invD + (size_t)(k + 1) * 4096, tid);
    }
}

// ---------------- finalize: Wc rows 0..511 = invD_k @ Agj[pivot rows, 512:1280] (bf16); rows 512..575 from C2|D21|D22 ----------------
__global__ __launch_bounds__(256) void k_finalize(const float* __restrict__ Agj, const float* __restrict__ invD,
                                                  const float* __restrict__ C2, const float* __restrict__ D21,
                                                  const float* __restrict__ D22, u16* __restrict__ Wc) {
    __shared__ __align__(16) float invDs[64 * 68];
    __shared__ __align__(16) float Ps[64 * 68];
    int tid = threadIdx.x, bx = blockIdx.x, by = blockIdx.y;
    int ty = tid >> 4, tx = tid & 15;
    if (by == 8) {
        #pragma unroll
        for (int ri = 0; ri < 4; ri++) {
            int q = ty * 4 + ri;
            int cbase = bx * 64 + tx * 4;
            f32x4 v;
            if (cbase < 512)      v = *(const f32x4*)(C2 + (size_t)q * 512 + cbase);
            else if (cbase < 640) v = *(const f32x4*)(D21 + (size_t)q * NST + (cbase - 512));
            else                  v = *(const f32x4*)(D22 + (size_t)q * NST + (cbase - 640));
            short4v o; o[0]=(short)f2bf(v[0]); o[1]=(short)f2bf(v[1]); o[2]=(short)f2bf(v[2]); o[3]=(short)f2bf(v[3]);
            *(short4v*)(Wc + (size_t)(512 + q) * KC + cbase) = o;
        }
        return;
    }
    int lr = tid >> 2, lc = tid & 3;
    #pragma unroll
    for (int q = 0; q < 4; q++) {
        *(f32x4*)&invDs[lr * 68 + lc * 16 + q * 4] = *(const f32x4*)(invD + (size_t)by * 4096 + lr * 64 + lc * 16 + q * 4);
        *(f32x4*)&Ps[lr * 68 + lc * 16 + q * 4]    = *(const f32x4*)(Agj + (size_t)(by * 64 + lr) * 1280 + 512 + bx * 64 + lc * 16 + q * 4);
    }
    __syncthreads();
    f32x4 s[4];
    #pragma unroll
    for (int ri = 0; ri < 4; ri++) s[ri] = (f32x4){0.f, 0.f, 0.f, 0.f};
    for (int kk = 0; kk < 64; kk++) {
        f32x4 pv = *(f32x4*)&Ps[kk * 68 + tx * 4];
        #pragma unroll
        for (int ri = 0; ri < 4; ri++) s[ri] += pv * invDs[(ty * 4 + ri) * 68 + kk];
    }
    #pragma unroll
    for (int ri = 0; ri < 4; ri++) {
        short4v o; o[0]=(short)f2bf(s[ri][0]); o[1]=(short)f2bf(s[ri][1]); o[2]=(short)f2bf(s[ri][2]); o[3]=(short)f2bf(s[ri][3]);
        *(short4v*)(Wc + (size_t)(by * 64 + ty * 4 + ri) * KC + bx * 64 + tx * 4) = o;
    }
}

// ---------------- blocked sequential tanh scan (right-looking), 16 lanes per batch row ----------------
// Lane lg owns i == lg (mod 16); corrv[b] = running v for i = b*16+lg (column-cyclic).
// Per 16-block: 16-step recurrence (tanh + shfl-broadcast + 1 FMA each), then rank-16
// update of all future blocks (independent FMAs, conflict-free LDS reads).
// eps written directly as bf16 into Ac cols 512:640.
__global__ __launch_bounds__(1024) void k_scan(const float* __restrict__ pre, const float* __restrict__ D11,
                                               const float* __restrict__ rlam, u16* __restrict__ Ac) {
    __shared__ __align__(16) float D11s[128 * 132];   // +4 pad: row-per-lane reads are 2-way (free)
    int tid = threadIdx.x;
    {   // stage D11 (fp32) into padded LDS: 16 floats per thread
        int r = tid >> 3, c = (tid & 7) * 16;
        const f32x4* src = (const f32x4*)(D11 + (size_t)r * 128 + c);
        f32x4 v0 = src[0], v1 = src[1], v2 = src[2], v3 = src[3];
        f32x4* dst = (f32x4*)&D11s[r * 132 + c];
        dst[0] = v0; dst[1] = v1; dst[2] = v2; dst[3] = v3;
    }
    int lg = tid & 15;
    int row = blockIdx.x * 64 + (tid >> 4);
    int gbase = (tid & 63) & ~15;   // group-base lane within wave
    const float L2E2 = 2.885390082f; // 2*log2(e)

    float corrv[8], a8[8];
    #pragma unroll
    for (int b = 0; b < 8; b++) {
        corrv[b] = pre[(size_t)row * 128 + b * 16 + lg];
        a8[b] = L2E2 * rlam[b * 16 + lg];
    }
    __syncthreads();

    #pragma unroll
    for (int b = 0; b < 8; b++) {
        // in-block D11 row slice: D11[b*16+lg][b*16 + 0..15] (zero for t >= lg)
        f32x4 dblk[4];
        #pragma unroll
        for (int q = 0; q < 4; q++)
            dblk[q] = *(const f32x4*)&D11s[(b * 16 + lg) * 132 + b * 16 + q * 4];
        float v = corrv[b];
        float a = a8[b];
        float e16[16];
        float myeps = 0.f;
        #pragma unroll
        for (int t = 0; t < 16; t++) {
            // fast tanh: 1 - 2/(exp2(a*v)+1), a = 2*log2e/lam
            float ex = __builtin_amdgcn_exp2f(a * v);
            float cand = 1.0f - 2.0f * __builtin_amdgcn_rcpf(ex + 1.0f);
            float e = __shfl(cand, gbase + t, 64);
            e16[t] = e;
            if (lg == t) myeps = e;
            v = fmaf(e, dblk[t >> 2][t & 3], v);
        }
        Ac[(size_t)row * KC + 512 + b * 16 + lg] = f2bf(myeps);
        // right-looking rank-16 update of future blocks
        #pragma unroll
        for (int bb = b + 1; bb < 8; bb++) {
            f32x4 dd[4];
            #pragma unroll
            for (int q = 0; q < 4; q++)
                dd[q] = *(const f32x4*)&D11s[(bb * 16 + lg) * 132 + b * 16 + q * 4];
            float acc = corrv[bb];
            #pragma unroll
            for (int t = 0; t < 16; t++)
                acc = fmaf(e16[t], dd[t >> 2][t & 3], acc);
            corrv[bb] = acc;
        }
    }
}

// ---------------- host ----------------
extern "C" void kernel_launch(void* const* d_in, const int* in_sizes, int n_in,
                              void* d_out, int out_size, void* d_ws, size_t ws_size,
                              hipStream_t stream) {
    const float* w_in  = (const float*)d_in[1];
    const float* xi_in = (const float*)d_in[2];
    const float* X   = (const float*)d_in[3];
    const float* Y   = (const float*)d_in[4];
    const float* B2  = (const float*)d_in[5];
    const float* C2  = (const float*)d_in[6];
    const float* D21 = (const float*)d_in[7];
    const float* D22 = (const float*)d_in[8];
    const float* D12 = (const float*)d_in[9];
    float* out_u  = (float*)d_out;                       // (BATCH,1,64)
    float* out_xi = (float*)d_out + (size_t)BATCH * NU;  // (BATCH,1,512)

    char* base = (char*)d_ws;
    size_t off = 0;
    auto carve = [&](size_t bytes) -> void* {
        void* p = base + off;
        off += (bytes + 255) & ~(size_t)255;
        return p;
    };
    u16*   XT   = (u16*)  carve((size_t)TW * TW * 2);
    u16*   Ac   = (u16*)  carve((size_t)BATCH * KC * 2);
    float* Hm   = (float*)carve((size_t)TW * TW * 4);
    float* Agj  = (float*)carve((size_t)512 * 1280 * 4);
    float* invD = (float*)carve((size_t)8 * 64 * 64 * 4);
    u16*   Wc   = (u16*)  carve((size_t)NC * KC * 2);
    u16*   W1   = (u16*)  carve((size_t)LL * KC * 2);
    float* pre  = (float*)carve((size_t)BATCH * LL * 4);
    float* D11  = (float*)carve((size_t)LL * LL * 4);
    float* rlam = (float*)carve((size_t)LL * 4);
    (void)ws_size; (void)in_sizes; (void)n_in; (void)out_size;

    // setup chain
    k_transpose<<<dim3(36, 36), 256, 0, stream>>>(X, XT);
    k_build_Ac<<<(BATCH * KC / 8 + 255) / 256, 256, 0, stream>>>(xi_in, w_in, Ac);
    // H = X^T X  (bf16 MFMA; +eps*I applied in k_derive)
    k_gemm<<<dim3(TW / 64, TW / 128), 256, 0, stream>>>(XT, TW, XT, TW, Hm, TW, 1 << 30, nullptr, 0, TW);
    k_derive<<<(512 * 1280 + 128 * 128 + 128 + 128 * KC + 255) / 256, 256, 0, stream>>>(
        Hm, Y, B2, D12, Agj, D11, rlam, W1);
    // blocked Gauss-Jordan on [E | Fm B1 B2] with fused next-diag inversion
    k_diaginv0<<<1, 256, 0, stream>>>(Agj, invD);
    for (int k = 0; k < 8; k++)
        k_elim<<<dim3(19 - k, 7), 256, 0, stream>>>(Agj, invD, k);
    k_finalize<<<dim3(12, 9), 256, 0, stream>>>(Agj, invD, C2, D21, D22, Wc);
    // batch side
    k_gemm<<<dim3(LL / 64, BATCH / 128), 256, 0, stream>>>(Ac, KC, W1, KC, pre, LL, 1 << 30, nullptr, 0, KC);
    k_scan<<<BATCH / 64, 1024, 0, stream>>>(pre, D11, rlam, Ac);
    k_gemm<<<dim3(NC / 64, BATCH / 128), 256, 0, stream>>>(Ac, KC, Wc, KC, out_xi, NXI, 512, out_u, NU, KC);
}

// Round 3
// 528.174 us; speedup vs baseline: 1.3197x; 1.0991x over previous
//
#include <hip/hip_runtime.h>
#include <cstddef>

// ---------------- constants ----------------
#define NXI   512
#define LL    128
#define NST   128
#define NU    64
#define BATCH 32768
#define TW    1152          // 2n + l
#define EPSC  0.001f
#define KC    768           // concat K: xi(512) | eps(128) | w(128)
#define NC    576           // concat N: xi'(512) | u(64)
#define NCP   640           // NC padded to 128

typedef unsigned short u16;
typedef __attribute__((ext_vector_type(8))) short   short8;
typedef __attribute__((ext_vector_type(4))) short   short4v;
typedef __attribute__((ext_vector_type(4))) float   f32x4;

__device__ __forceinline__ u16 f2bf(float f) {
    unsigned u = __float_as_uint(f);
    u += 0x7FFFu + ((u >> 16) & 1u);   // RNE
    return (u16)(u >> 16);
}

// ---------------- transpose+convert X -> XT (bf16), XT[i][k] = X[k][i] ----------------
__global__ __launch_bounds__(256) void k_transpose(const float* __restrict__ X, u16* __restrict__ XT) {
    __shared__ float t[32][33];
    int tx = threadIdx.x & 31, ty = threadIdx.x >> 5;
    int bx = blockIdx.x, by = blockIdx.y;
    #pragma unroll
    for (int q = 0; q < 4; q++) {
        int r = ty + q * 8;
        t[r][tx] = X[(size_t)(by * 32 + r) * TW + bx * 32 + tx];
    }
    __syncthreads();
    #pragma unroll
    for (int q = 0; q < 4; q++) {
        int r = ty + q * 8;
        XT[(size_t)(bx * 32 + r) * TW + by * 32 + tx] = f2bf(t[tx][r]);
    }
}

// ---------------- build Ac = [bf16(xi) | (eps gap) | bf16(w)] (BATCH x 768) ----------------
// eps columns (512:640) are written later by k_scan; skip zero-filling them.
__global__ __launch_bounds__(256) void k_build_Ac(const float* __restrict__ xi, const float* __restrict__ w,
                                                  u16* __restrict__ Ac) {
    size_t t = (size_t)blockIdx.x * 256 + threadIdx.x;   // chunk id, 8 elems each
    int b = (int)(t / 80), ch = (int)(t % 80);
    const float* src;
    int col;
    if (ch < 64) { src = xi + (size_t)b * NXI + ch * 8;        col = ch * 8; }
    else         { src = w  + (size_t)b * NST + (ch - 64) * 8; col = 640 + (ch - 64) * 8; }
    f32x4 a = ((const f32x4*)src)[0], c = ((const f32x4*)src)[1];
    short8 o;
    o[0]=(short)f2bf(a[0]); o[1]=(short)f2bf(a[1]); o[2]=(short)f2bf(a[2]); o[3]=(short)f2bf(a[3]);
    o[4]=(short)f2bf(c[0]); o[5]=(short)f2bf(c[1]); o[6]=(short)f2bf(c[2]); o[7]=(short)f2bf(c[3]);
    *(short8*)(Ac + (size_t)b * KC + col) = o;
}

// ---------------- m97-style bf16 MFMA GEMM: C = A @ W^T ----------------
// BM=128 BN=128 BK=32, 256 threads (4 waves in 2x2), global_load_lds width-16 staging,
// 8 ds_read_b128 + 16 MFMA per K-step. 1-D grid with optional XCD-aware swizzle:
// all nbx N-blocks of one M-band land on the same XCD (id&7) consecutively -> A-tile L2-resident.
__global__ __launch_bounds__(256) void k_gemm2(const u16* __restrict__ A, int lda,
                                               const u16* __restrict__ W, int ldw,
                                               float* __restrict__ C0, int ldc0, int nsplit,
                                               float* __restrict__ C1, int ldc1,
                                               int K, int nbx, int ntrue, int swz) {
    __shared__ __align__(16) u16 As[128 * 32];
    __shared__ __align__(16) u16 Bs[128 * 32];
    int id = blockIdx.x;
    int bx, by;
    if (swz) {
        int j = id >> 3;
        int per = (int)(gridDim.x >> 3) / nbx;     // M-bands per XCD (requires nby%8==0)
        by = (id & 7) * per + j / nbx;
        bx = j - (j / nbx) * nbx;
    } else {
        by = id / nbx;
        bx = id - by * nbx;
    }
    const int tid = threadIdx.x;
    const int wave = tid >> 6, lane = tid & 63, quad = lane >> 4, l16 = lane & 15;
    const int bm0 = by * 128, bn0 = bx * 128;
    const int srow = tid >> 2, sch = (tid & 3) * 8;
    const u16* ga0 = A + (size_t)(bm0 + srow) * lda + sch;
    const u16* ga1 = ga0 + (size_t)64 * lda;
    const u16* gb0 = W + (size_t)(bn0 + srow) * ldw + sch;
    const u16* gb1 = gb0 + (size_t)64 * ldw;
    u16* la = As + wave * 512;     // wave-uniform LDS dest (lane-ordered, contiguous)
    u16* lb = Bs + wave * 512;
    const int mb = (wave >> 1) * 64, nb = (wave & 1) * 64;

    f32x4 acc[4][4];
    #pragma unroll
    for (int i = 0; i < 4; i++)
        #pragma unroll
        for (int j = 0; j < 4; j++) acc[i][j] = (f32x4){0.f, 0.f, 0.f, 0.f};

    for (int kt = 0; kt < K; kt += 32) {
        __syncthreads();
        __builtin_amdgcn_global_load_lds((void*)(ga0 + kt), (void*)la,          16, 0, 0);
        __builtin_amdgcn_global_load_lds((void*)(ga1 + kt), (void*)(la + 2048), 16, 0, 0);
        __builtin_amdgcn_global_load_lds((void*)(gb0 + kt), (void*)lb,          16, 0, 0);
        __builtin_amdgcn_global_load_lds((void*)(gb1 + kt), (void*)(lb + 2048), 16, 0, 0);
        __syncthreads();
        short8 af[4], bf[4];
        #pragma unroll
        for (int mt = 0; mt < 4; mt++) af[mt] = *(const short8*)&As[(mb + mt * 16 + l16) * 32 + quad * 8];
        #pragma unroll
        for (int nt = 0; nt < 4; nt++) bf[nt] = *(const short8*)&Bs[(nb + nt * 16 + l16) * 32 + quad * 8];
        #pragma unroll
        for (int mt = 0; mt < 4; mt++)
            #pragma unroll
            for (int nt = 0; nt < 4; nt++)
                acc[mt][nt] = __builtin_amdgcn_mfma_f32_16x16x32_bf16(af[mt], bf[nt], acc[mt][nt], 0, 0, 0);
    }
    // epilogue: per 16x16 tile, D[row=quad*4+r][col=l16] (m89-verified layout)
    #pragma unroll
    for (int mt = 0; mt < 4; mt++)
        #pragma unroll
        for (int nt = 0; nt < 4; nt++)
            #pragma unroll
            for (int r = 0; r < 4; r++) {
                int row = bm0 + mb + mt * 16 + quad * 4 + r;
                int col = bn0 + nb + nt * 16 + l16;
                if (col < ntrue) {
                    float v = acc[mt][nt][r];
                    if (col < nsplit) C0[(size_t)row * ldc0 + col] = v;
                    else              C1[(size_t)row * ldc1 + (col - nsplit)] = v;
                }
            }
}

// ---------------- derive params from H, build GJ-augmented [E | Fm B1 B2], D11, rlam, W1 ----------------
__global__ __launch_bounds__(256) void k_derive(const float* __restrict__ Hm, const float* __restrict__ Y,
                                                const float* __restrict__ B2, const float* __restrict__ D12,
                                                float* __restrict__ Agj, float* __restrict__ D11,
                                                float* __restrict__ rlam, u16* __restrict__ W1) {
    int idx = blockIdx.x * 256 + threadIdx.x;
    const int n0 = 512 * 1280, n1 = 128 * 128, n2 = 128, n3 = 128 * KC;
    if (idx < n0) {
        int i = idx / 1280, j = idx % 1280;
        float val;
        if (j < 512) {
            val = 0.5f * (Hm[(size_t)i * TW + j] + Hm[(size_t)(640 + i) * TW + 640 + j]
                          + Y[(size_t)i * 512 + j] - Y[(size_t)j * 512 + i]);
            if (i == j) val += EPSC;
        } else if (j < 1024) {
            val = Hm[(size_t)(640 + i) * TW + (j - 512)];           // Fm = H31
        } else if (j < 1152) {
            val = Hm[(size_t)(640 + i) * TW + 512 + (j - 1024)];    // B1 = H32
        } else {
            val = B2[(size_t)i * NST + (j - 1152)];
        }
        Agj[idx] = val;
        return;
    }
    idx -= n0;
    if (idx < n1) {
        int i = idx >> 7, j = idx & 127;
        D11[idx] = (j < i) ? -Hm[(size_t)(512 + i) * TW + 512 + j] : 0.f;  // -tril(H22,-1)
        return;
    }
    idx -= n1;
    if (idx < n2) {
        rlam[idx] = 2.0f / (Hm[(size_t)(512 + idx) * TW + 512 + idx] + EPSC);  // 1/(0.5*diag(H22))
        return;
    }
    idx -= n2;
    if (idx < n3) {
        int i = idx / KC, c = idx % KC;
        float v;
        if (c < 512)      v = -Hm[(size_t)(512 + i) * TW + c];      // C1 = -H21
        else if (c < 640) v = 0.f;                                  // eps slot unused for pre
        else              v = D12[(size_t)i * NST + (c - 640)];
        W1[(size_t)i * KC + c] = f2bf(v);
    }
}

// ---------------- 64x64 in-block Gauss-Jordan inverse (no pivoting) ----------------
__device__ __forceinline__ void invert64(float* Cl, float* Sa, float* Sb, float* mcol,
                                         float* rp, float* __restrict__ invOut, int tid) {
    int r = tid >> 2, c = tid & 3;
    float a[16], b[16];
    #pragma unroll
    for (int q = 0; q < 4; q++) {
        f32x4 v = *(f32x4*)&Cl[r * 68 + c * 16 + q * 4];
        a[q*4+0]=v[0]; a[q*4+1]=v[1]; a[q*4+2]=v[2]; a[q*4+3]=v[3];
    }
    #pragma unroll
    for (int j = 0; j < 16; j++) b[j] = (c * 16 + j == r) ? 1.f : 0.f;

    #pragma unroll
    for (int k = 0; k < 64; k++) {
        const int kc = k >> 4, kl = k & 15;
        if (r == k) {
            #pragma unroll
            for (int q = 0; q < 4; q++) {
                *(f32x4*)&Sa[c * 16 + q * 4] = (f32x4){a[q*4], a[q*4+1], a[q*4+2], a[q*4+3]};
                *(f32x4*)&Sb[c * 16 + q * 4] = (f32x4){b[q*4], b[q*4+1], b[q*4+2], b[q*4+3]};
            }
        }
        if (c == kc) {
            mcol[r] = a[kl];
            if (r == k) rp[0] = 1.0f / a[kl];
        }
        __syncthreads();
        float m = (mcol[r] - ((r == k) ? 1.0f : 0.0f)) * rp[0];
        #pragma unroll
        for (int q = 0; q < 4; q++) {
            f32x4 sa = *(f32x4*)&Sa[c * 16 + q * 4];
            f32x4 sb = *(f32x4*)&Sb[c * 16 + q * 4];
            a[q*4+0] = fmaf(-m, sa[0], a[q*4+0]); a[q*4+1] = fmaf(-m, sa[1], a[q*4+1]);
            a[q*4+2] = fmaf(-m, sa[2], a[q*4+2]); a[q*4+3] = fmaf(-m, sa[3], a[q*4+3]);
            b[q*4+0] = fmaf(-m, sb[0], b[q*4+0]); b[q*4+1] = fmaf(-m, sb[1], b[q*4+1]);
            b[q*4+2] = fmaf(-m, sb[2], b[q*4+2]); b[q*4+3] = fmaf(-m, sb[3], b[q*4+3]);
        }
        __syncthreads();
    }
    #pragma unroll
    for (int q = 0; q < 4; q++)
        *(f32x4*)&invOut[r * 64 + c * 16 + q * 4] = (f32x4){b[q*4], b[q*4+1], b[q*4+2], b[q*4+3]};
}

__global__ __launch_bounds__(256) void k_diaginv0(const float* __restrict__ Agj, float* __restrict__ invD) {
    __shared__ __align__(16) float Cl[64 * 68];
    __shared__ float Sa[64], Sb[64], mcol[64], rp[1];
    int tid = threadIdx.x, r = tid >> 2, c4 = tid & 3;
    #pragma unroll
    for (int q = 0; q < 4; q++)
        *(f32x4*)&Cl[r * 68 + c4 * 16 + q * 4] = *(const f32x4*)(Agj + (size_t)r * 1280 + c4 * 16 + q * 4);
    __syncthreads();
    invert64(Cl, Sa, Sb, mcol, rp, invD, tid);
}

// ---------------- GJ eliminate step k ----------------
__global__ __launch_bounds__(256) void k_elim(float* __restrict__ Agj, float* __restrict__ invD, int k) {
    __shared__ __align__(16) float invDs[64 * 68];
    __shared__ __align__(16) float Ps[64 * 68];
    __shared__ __align__(16) float Ss[64 * 68];
    __shared__ __align__(16) float Ms[64 * 68];
    __shared__ float Sa[64], Sb[64], mcol[64], rp[1];
    int tid = threadIdx.x;
    int by = blockIdx.y, bx = blockIdx.x;
    int rb = by + (by >= k ? 1 : 0);
    int cb = k + 1 + bx;
    int lr = tid >> 2, lc = tid & 3;
    #pragma unroll
    for (int q = 0; q < 4; q++) {
        *(f32x4*)&invDs[lr * 68 + lc * 16 + q * 4] = *(const f32x4*)(invD + (size_t)k * 4096 + lr * 64 + lc * 16 + q * 4);
        *(f32x4*)&Ps[lr * 68 + lc * 16 + q * 4]    = *(const f32x4*)(Agj + (size_t)(k * 64 + lr) * 1280 + cb * 64 + lc * 16 + q * 4);
        *(f32x4*)&Ms[lr * 68 + lc * 16 + q * 4]    = *(const f32x4*)(Agj + (size_t)(rb * 64 + lr) * 1280 + k * 64 + lc * 16 + q * 4);
    }
    __syncthreads();
    int ty = tid >> 4, tx = tid & 15;
    f32x4 s[4];
    #pragma unroll
    for (int ri = 0; ri < 4; ri++) s[ri] = (f32x4){0.f, 0.f, 0.f, 0.f};
    for (int kk = 0; kk < 64; kk++) {
        f32x4 pv = *(f32x4*)&Ps[kk * 68 + tx * 4];
        #pragma unroll
        for (int ri = 0; ri < 4; ri++) s[ri] += pv * invDs[(ty * 4 + ri) * 68 + kk];
    }
    #pragma unroll
    for (int ri = 0; ri < 4; ri++) *(f32x4*)&Ss[(ty * 4 + ri) * 68 + tx * 4] = s[ri];
    __syncthreads();
    f32x4 accv[4];
    #pragma unroll
    for (int ri = 0; ri < 4; ri++)
        accv[ri] = *(const f32x4*)(Agj + (size_t)(rb * 64 + ty * 4 + ri) * 1280 + cb * 64 + tx * 4);
    for (int kk = 0; kk < 64; kk++) {
        f32x4 sv = *(f32x4*)&Ss[kk * 68 + tx * 4];
        #pragma unroll
        for (int ri = 0; ri < 4; ri++) accv[ri] -= sv * Ms[(ty * 4 + ri) * 68 + kk];
    }
    #pragma unroll
    for (int ri = 0; ri < 4; ri++)
        *(f32x4*)(Agj + (size_t)(rb * 64 + ty * 4 + ri) * 1280 + cb * 64 + tx * 4) = accv[ri];
    if (k < 7 && bx == 0 && by == k) {
        __syncthreads();
        #pragma unroll
        for (int ri = 0; ri < 4; ri++) *(f32x4*)&Ps[(ty * 4 + ri) * 68 + tx * 4] = accv[ri];
        __syncthreads();
        invert64(Ps, Sa, Sb, mcol, rp, invD + (size_t)(k + 1) * 4096, tid);
    }
}

// ---------------- finalize: Wc rows 0..511 = invD_k @ Agj[pivot rows, 512:1280] (bf16);
// rows 512..575 from C2|D21|D22; rows 576..639 zero padding ----------------
__global__ __launch_bounds__(256) void k_finalize(const float* __restrict__ Agj, const float* __restrict__ invD,
                                                  const float* __restrict__ C2, const float* __restrict__ D21,
                                                  const float* __restrict__ D22, u16* __restrict__ Wc) {
    __shared__ __align__(16) float invDs[64 * 68];
    __shared__ __align__(16) float Ps[64 * 68];
    int tid = threadIdx.x, bx = blockIdx.x, by = blockIdx.y;
    int ty = tid >> 4, tx = tid & 15;
    if (by >= 8) {
        #pragma unroll
        for (int ri = 0; ri < 4; ri++) {
            int q = ty * 4 + ri;
            int row = 512 + (by - 8) * 64 + q;
            int cbase = bx * 64 + tx * 4;
            short4v o;
            if (by == 8) {
                f32x4 v;
                if (cbase < 512)      v = *(const f32x4*)(C2 + (size_t)q * 512 + cbase);
                else if (cbase < 640) v = *(const f32x4*)(D21 + (size_t)q * NST + (cbase - 512));
                else                  v = *(const f32x4*)(D22 + (size_t)q * NST + (cbase - 640));
                o[0]=(short)f2bf(v[0]); o[1]=(short)f2bf(v[1]); o[2]=(short)f2bf(v[2]); o[3]=(short)f2bf(v[3]);
            } else {
                o[0]=0; o[1]=0; o[2]=0; o[3]=0;
            }
            *(short4v*)(Wc + (size_t)row * KC + cbase) = o;
        }
        return;
    }
    int lr = tid >> 2, lc = tid & 3;
    #pragma unroll
    for (int q = 0; q < 4; q++) {
        *(f32x4*)&invDs[lr * 68 + lc * 16 + q * 4] = *(const f32x4*)(invD + (size_t)by * 4096 + lr * 64 + lc * 16 + q * 4);
        *(f32x4*)&Ps[lr * 68 + lc * 16 + q * 4]    = *(const f32x4*)(Agj + (size_t)(by * 64 + lr) * 1280 + 512 + bx * 64 + lc * 16 + q * 4);
    }
    __syncthreads();
    f32x4 s[4];
    #pragma unroll
    for (int ri = 0; ri < 4; ri++) s[ri] = (f32x4){0.f, 0.f, 0.f, 0.f};
    for (int kk = 0; kk < 64; kk++) {
        f32x4 pv = *(f32x4*)&Ps[kk * 68 + tx * 4];
        #pragma unroll
        for (int ri = 0; ri < 4; ri++) s[ri] += pv * invDs[(ty * 4 + ri) * 68 + kk];
    }
    #pragma unroll
    for (int ri = 0; ri < 4; ri++) {
        short4v o; o[0]=(short)f2bf(s[ri][0]); o[1]=(short)f2bf(s[ri][1]); o[2]=(short)f2bf(s[ri][2]); o[3]=(short)f2bf(s[ri][3]);
        *(short4v*)(Wc + (size_t)(by * 64 + ty * 4 + ri) * KC + bx * 64 + tx * 4) = o;
    }
}

// ---------------- blocked sequential tanh scan (right-looking), 16 lanes per batch row ----------------
__global__ __launch_bounds__(1024) void k_scan(const float* __restrict__ pre, const float* __restrict__ D11,
                                               const float* __restrict__ rlam, u16* __restrict__ Ac) {
    __shared__ __align__(16) float D11s[128 * 132];   // +4 pad: row-per-lane reads are 2-way (free)
    int tid = threadIdx.x;
    {
        int r = tid >> 3, c = (tid & 7) * 16;
        const f32x4* src = (const f32x4*)(D11 + (size_t)r * 128 + c);
        f32x4 v0 = src[0], v1 = src[1], v2 = src[2], v3 = src[3];
        f32x4* dst = (f32x4*)&D11s[r * 132 + c];
        dst[0] = v0; dst[1] = v1; dst[2] = v2; dst[3] = v3;
    }
    int lg = tid & 15;
    int row = blockIdx.x * 64 + (tid >> 4);
    int gbase = (tid & 63) & ~15;
    const float L2E2 = 2.885390082f; // 2*log2(e)

    float corrv[8], a8[8];
    #pragma unroll
    for (int b = 0; b < 8; b++) {
        corrv[b] = pre[(size_t)row * 128 + b * 16 + lg];
        a8[b] = L2E2 * rlam[b * 16 + lg];
    }
    __syncthreads();

    #pragma unroll
    for (int b = 0; b < 8; b++) {
        f32x4 dblk[4];
        #pragma unroll
        for (int q = 0; q < 4; q++)
            dblk[q] = *(const f32x4*)&D11s[(b * 16 + lg) * 132 + b * 16 + q * 4];
        float v = corrv[b];
        float a = a8[b];
        float e16[16];
        float myeps = 0.f;
        #pragma unroll
        for (int t = 0; t < 16; t++) {
            float ex = __builtin_amdgcn_exp2f(a * v);
            float cand = 1.0f - 2.0f * __builtin_amdgcn_rcpf(ex + 1.0f);
            float e = __shfl(cand, gbase + t, 64);
            e16[t] = e;
            if (lg == t) myeps = e;
            v = fmaf(e, dblk[t >> 2][t & 3], v);
        }
        Ac[(size_t)row * KC + 512 + b * 16 + lg] = f2bf(myeps);
        #pragma unroll
        for (int bb = b + 1; bb < 8; bb++) {
            f32x4 dd[4];
            #pragma unroll
            for (int q = 0; q < 4; q++)
                dd[q] = *(const f32x4*)&D11s[(bb * 16 + lg) * 132 + b * 16 + q * 4];
            float acc = corrv[bb];
            #pragma unroll
            for (int t = 0; t < 16; t++)
                acc = fmaf(e16[t], dd[t >> 2][t & 3], acc);
            corrv[bb] = acc;
        }
    }
}

// ---------------- host ----------------
extern "C" void kernel_launch(void* const* d_in, const int* in_sizes, int n_in,
                              void* d_out, int out_size, void* d_ws, size_t ws_size,
                              hipStream_t stream) {
    const float* w_in  = (const float*)d_in[1];
    const float* xi_in = (const float*)d_in[2];
    const float* X   = (const float*)d_in[3];
    const float* Y   = (const float*)d_in[4];
    const float* B2  = (const float*)d_in[5];
    const float* C2  = (const float*)d_in[6];
    const float* D21 = (const float*)d_in[7];
    const float* D22 = (const float*)d_in[8];
    const float* D12 = (const float*)d_in[9];
    float* out_u  = (float*)d_out;                       // (BATCH,1,64)
    float* out_xi = (float*)d_out + (size_t)BATCH * NU;  // (BATCH,1,512)

    char* base = (char*)d_ws;
    size_t off = 0;
    auto carve = [&](size_t bytes) -> void* {
        void* p = base + off;
        off += (bytes + 255) & ~(size_t)255;
        return p;
    };
    u16*   XT   = (u16*)  carve((size_t)TW * TW * 2);
    u16*   Ac   = (u16*)  carve((size_t)BATCH * KC * 2);
    float* Hm   = (float*)carve((size_t)TW * TW * 4);
    float* Agj  = (float*)carve((size_t)512 * 1280 * 4);
    float* invD = (float*)carve((size_t)8 * 64 * 64 * 4);
    u16*   Wc   = (u16*)  carve((size_t)NCP * KC * 2);
    u16*   W1   = (u16*)  carve((size_t)LL * KC * 2);
    float* pre  = (float*)carve((size_t)BATCH * LL * 4);
    float* D11  = (float*)carve((size_t)LL * LL * 4);
    float* rlam = (float*)carve((size_t)LL * 4);
    (void)ws_size; (void)in_sizes; (void)n_in; (void)out_size;

    // setup chain
    k_transpose<<<dim3(36, 36), 256, 0, stream>>>(X, XT);
    k_build_Ac<<<BATCH * 80 / 256, 256, 0, stream>>>(xi_in, w_in, Ac);
    // H = X^T X  (bf16 MFMA; +eps*I applied in k_derive). M=N=K=1152, no swizzle (nby=9)
    k_gemm2<<<81, 256, 0, stream>>>(XT, TW, XT, TW, Hm, TW, 1 << 30, nullptr, 0, TW, 9, TW, 0);
    k_derive<<<(512 * 1280 + 128 * 128 + 128 + 128 * KC + 255) / 256, 256, 0, stream>>>(
        Hm, Y, B2, D12, Agj, D11, rlam, W1);
    // blocked Gauss-Jordan on [E | Fm B1 B2] with fused next-diag inversion
    k_diaginv0<<<1, 256, 0, stream>>>(Agj, invD);
    for (int k = 0; k < 8; k++)
        k_elim<<<dim3(19 - k, 7), 256, 0, stream>>>(Agj, invD, k);
    k_finalize<<<dim3(12, 10), 256, 0, stream>>>(Agj, invD, C2, D21, D22, Wc);
    // batch side
    k_gemm2<<<256, 256, 0, stream>>>(Ac, KC, W1, KC, pre, LL, 1 << 30, nullptr, 0, KC, 1, LL, 1);
    k_scan<<<BATCH / 64, 1024, 0, stream>>>(pre, D11, rlam, Ac);
    k_gemm2<<<1280, 256, 0, stream>>>(Ac, KC, Wc, KC, out_xi, NXI, 512, out_u, NU, KC, 5, NC, 1);
}